// Round 6
// baseline (42.835 us; speedup 1.0000x reference)
//
#include <hip/hip_runtime.h>
#include <math.h>

#define ND 64
#define NPTS (4 * ND * ND * ND)   // 1,048,576
#define SXG (ND * ND * 3)         // 12288
#define SYG (ND * 3)              // 192

struct f3 { float v[3]; };

__device__ __forceinline__ f3 comb2(float a, const f3& X, float s, const f3& Y) {
    f3 r;
#pragma unroll
    for (int c = 0; c < 3; c++) r.v[c] = a * X.v[c] + s * Y.v[c];
    return r;
}
__device__ __forceinline__ f3 comb3(float a, const f3& X, float s, const f3& Y, float u, const f3& Z) {
    f3 r;
#pragma unroll
    for (int c = 0; c < 3; c++) r.v[c] = a * X.v[c] + s * Y.v[c] + u * Z.v[c];
    return r;
}
// per-lane select: cond ? 2*A - B : C   (ghost extrapolation depth 1)
__device__ __forceinline__ f3 selg1(bool cond, const f3& A, const f3& B, const f3& C) {
    f3 r;
#pragma unroll
    for (int c = 0; c < 3; c++) r.v[c] = cond ? 2.f * A.v[c] - B.v[c] : C.v[c];
    return r;
}

// physics residual norm; H symmetric [c][6]: 0=xx 1=yy 2=zz 3=xy 4=xz 5=yz
__device__ __forceinline__ float phys_norm(const float F[3][3], const float H[3][6]) {
    constexpr int SYM[3][3] = {{0, 3, 4}, {3, 1, 5}, {4, 5, 2}};

    float cof[3][3];
#pragma unroll
    for (int i = 0; i < 3; i++) {
        const int i1 = (i + 1) % 3, i2 = (i + 2) % 3;
#pragma unroll
        for (int j = 0; j < 3; j++) {
            const int j1 = (j + 1) % 3, j2 = (j + 2) % 3;
            cof[i][j] = F[i1][j1] * F[i2][j2] - F[i1][j2] * F[i2][j1];
        }
    }

    float gc0[3][3], trg[3];
#pragma unroll
    for (int m = 0; m < 3; m++) {
        const int m1 = (m + 1) % 3, m2 = (m + 2) % 3;
        trg[m] = 0.0f;
#pragma unroll
        for (int i = 0; i < 3; i++) {
            const int i1 = (i + 1) % 3, i2 = (i + 2) % 3;
#pragma unroll
            for (int j = 0; j < 3; j++) {
                if (i == 0 || i == j) {
                    const float g = F[m2][i2] * H[m1][SYM[i1][j]] + F[m1][i1] * H[m2][SYM[i2][j]]
                                  - F[m2][i1] * H[m1][SYM[i2][j]] - F[m1][i2] * H[m2][SYM[i1][j]];
                    if (i == 0) gc0[m][j] = g;
                    if (i == j) trg[m] += g;
                }
            }
        }
    }

    const float J = F[0][0] * cof[0][0] + F[1][0] * cof[1][0] + F[2][0] * cof[2][0] + 1e-8f;
    const float invJ = 1.0f / J;

    float gJ[3];
#pragma unroll
    for (int j = 0; j < 3; j++) {
        gJ[j] = cof[0][0] * H[0][SYM[0][j]] + cof[1][0] * H[1][SYM[0][j]] + cof[2][0] * H[2][SYM[0][j]]
              + gc0[0][j] * F[0][0] + gc0[1][j] * F[1][0] + gc0[2][j] * F[2][0];
    }

    const float MU = 1000.0f, LMBD = 5000.0f;
    const float halfL = 0.5f * LMBD * (J * J - 1.0f);
    float r[3];
#pragma unroll
    for (int m = 0; m < 3; m++) {
        const float s1 = gJ[0] * cof[m][0] + gJ[1] * cof[m][1] + gJ[2] * cof[m][2];
        const float divInv = -invJ * invJ * s1 + invJ * trg[m];
        const float divF = H[m][0] + H[m][1] + H[m][2];
        float v = MU * (divF - divInv) + halfL * divInv + LMBD * s1;
        r[m] = (v != v) ? 0.0f : v;   // NaN -> 0
    }
    return sqrtf(r[0] * r[0] + r[1] * r[1] + r[2] * r[2]);
}

__global__ __launch_bounds__(512) void phys_loss_kernel(
        const float* __restrict__ pred,
        const float* __restrict__ targ,
        float* __restrict__ out) {
    const int t = threadIdx.x;
    const int lane = t & 63;
    const int wid = t >> 6;
    const int cid = blockIdx.x * 8 + wid;   // column id
    const int y = cid & 63;
    const int x = (cid >> 6) & 63;
    const int b = cid >> 12;
    const int z = lane;

    const float* __restrict__ pb = pred + (size_t)b * (ND * SXG);

    const int xp1i = min(x + 1, 63), xm1i = max(x - 1, 0);
    const int xp2i = min(x + 2, 63), xm2i = max(x - 2, 0);
    const int yp1i = min(y + 1, 63), ym1i = max(y - 1, 0);
    const int yp2i = min(y + 2, 63), ym2i = max(y - 2, 0);
    const int zp1i = min(z + 1, 63), zm1i = max(z - 1, 0);
    const int zp2i = min(z + 2, 63), zm2i = max(z - 2, 0);

#define LD(xx, yy, zz) (*(const f3*)(pb + (size_t)((xx) * SXG + (yy) * SYG + (zz) * 3)))
    // own column, z-2..z+2 (clamped addresses; ghosts fixed below)
    f3 c_m2 = LD(x, y, zm2i), c_m1 = LD(x, y, zm1i), c_0 = LD(x, y, z),
       c_p1 = LD(x, y, zp1i), c_p2 = LD(x, y, zp2i);
    // first-ring columns at z-1, z, z+1
    f3 xp_m = LD(xp1i, y, zm1i), xp_0 = LD(xp1i, y, z), xp_p = LD(xp1i, y, zp1i);
    f3 xm_m = LD(xm1i, y, zm1i), xm_0 = LD(xm1i, y, z), xm_p = LD(xm1i, y, zp1i);
    f3 yp_m = LD(x, yp1i, zm1i), yp_0 = LD(x, yp1i, z), yp_p = LD(x, yp1i, zp1i);
    f3 ym_m = LD(x, ym1i, zm1i), ym_0 = LD(x, ym1i, z), ym_p = LD(x, ym1i, zp1i);
    // second-ring / diagonal columns at z only
    f3 xp2 = LD(xp2i, y, z), xm2 = LD(xm2i, y, z);
    f3 yp2 = LD(x, yp2i, z), ym2 = LD(x, ym2i, z);
    f3 pp = LD(xp1i, yp1i, z), pm = LD(xp1i, ym1i, z);
    f3 mp = LD(xm1i, yp1i, z), mm = LD(xm1i, ym1i, z);
#undef LD

    // ---- z ghost fixups (per-lane selects; ghost identities verified r3) ----
    const bool l0 = (z == 0), l1 = (z == 1), l62 = (z == 62), l63 = (z == 63);

    f3 d1 = selg1(l63, c_0, c_m1, c_p1);        // C at z+1
    f3 u1 = selg1(l0,  c_0, c_p1, c_m1);        // C at z-1
    f3 d2, u2;
#pragma unroll
    for (int c = 0; c < 3; c++) {
        d2.v[c] = l63 ? 4.f * c_0.v[c] - 4.f * c_m1.v[c] + c_m2.v[c]
                      : (l62 ? 2.f * d1.v[c] - c_0.v[c] : c_p2.v[c]);
        u2.v[c] = l0  ? 4.f * c_0.v[c] - 4.f * c_p1.v[c] + c_p2.v[c]
                      : (l1 ? 2.f * u1.v[c] - c_0.v[c] : c_m2.v[c]);
    }
    { f3 a = selg1(l63, xp_0, xp_m, xp_p), bq = selg1(l0, xp_0, xp_p, xp_m); xp_p = a; xp_m = bq; }
    { f3 a = selg1(l63, xm_0, xm_m, xm_p), bq = selg1(l0, xm_0, xm_p, xm_m); xm_p = a; xm_m = bq; }
    { f3 a = selg1(l63, yp_0, yp_m, yp_p), bq = selg1(l0, yp_0, yp_p, yp_m); yp_p = a; yp_m = bq; }
    { f3 a = selg1(l63, ym_0, ym_m, ym_p), bq = selg1(l0, ym_0, ym_p, ym_m); ym_p = a; ym_m = bq; }

    // ---- y ghost fixups (wave-uniform) ----
    if (y == 0) {
        ym_m = comb2(2.f, u1, -1.f, yp_m);
        ym_0 = comb2(2.f, c_0, -1.f, yp_0);
        ym_p = comb2(2.f, d1, -1.f, yp_p);
        ym2  = comb3(4.f, c_0, -4.f, yp_0, 1.f, yp2);
        pm   = comb2(2.f, xp_0, -1.f, pp);
        mm   = comb2(2.f, xm_0, -1.f, mp);
    } else if (y == 1) {
        ym2 = comb2(2.f, ym_0, -1.f, c_0);
    } else if (y == 62) {
        yp2 = comb2(2.f, yp_0, -1.f, c_0);
    } else if (y == 63) {
        yp_m = comb2(2.f, u1, -1.f, ym_m);
        yp_0 = comb2(2.f, c_0, -1.f, ym_0);
        yp_p = comb2(2.f, d1, -1.f, ym_p);
        yp2  = comb3(4.f, c_0, -4.f, ym_0, 1.f, ym2);
        pp   = comb2(2.f, xp_0, -1.f, pm);
        mp   = comb2(2.f, xm_0, -1.f, mm);
    }
    // ---- x ghost fixups (wave-uniform; after y so corners use fixed cols) ----
    if (x == 0) {
        xm_m = comb2(2.f, u1, -1.f, xp_m);
        xm_0 = comb2(2.f, c_0, -1.f, xp_0);
        xm_p = comb2(2.f, d1, -1.f, xp_p);
        xm2  = comb3(4.f, c_0, -4.f, xp_0, 1.f, xp2);
        mp   = comb2(2.f, yp_0, -1.f, pp);
        mm   = comb2(2.f, ym_0, -1.f, pm);
    } else if (x == 1) {
        xm2 = comb2(2.f, xm_0, -1.f, c_0);
    } else if (x == 62) {
        xp2 = comb2(2.f, xp_0, -1.f, c_0);
    } else if (x == 63) {
        xp_m = comb2(2.f, u1, -1.f, xm_m);
        xp_0 = comb2(2.f, c_0, -1.f, xm_0);
        xp_p = comb2(2.f, d1, -1.f, xm_p);
        xp2  = comb3(4.f, c_0, -4.f, xm_0, 1.f, xm2);
        pp   = comb2(2.f, yp_0, -1.f, mp);
        pm   = comb2(2.f, ym_0, -1.f, mm);
    }

    // ---- F and H ----
    float F[3][3], H[3][6];
#pragma unroll
    for (int c = 0; c < 3; c++) {
        F[c][0] = 0.5f * (xp_0.v[c] - xm_0.v[c]) + ((c == 0) ? 1.f : 0.f);
        F[c][1] = 0.5f * (yp_0.v[c] - ym_0.v[c]) + ((c == 1) ? 1.f : 0.f);
        F[c][2] = 0.5f * (d1.v[c] - u1.v[c]) + ((c == 2) ? 1.f : 0.f);
        H[c][0] = 0.25f * (xp2.v[c] + xm2.v[c]) - 0.5f * c_0.v[c];
        H[c][1] = 0.25f * (yp2.v[c] + ym2.v[c]) - 0.5f * c_0.v[c];
        H[c][2] = 0.25f * (d2.v[c] + u2.v[c]) - 0.5f * c_0.v[c];
        H[c][3] = 0.25f * ((pp.v[c] - mp.v[c]) - (pm.v[c] - mm.v[c]));
        H[c][4] = 0.25f * ((xp_p.v[c] - xm_p.v[c]) - (xp_m.v[c] - xm_m.v[c]));
        H[c][5] = 0.25f * ((yp_p.v[c] - ym_p.v[c]) - (yp_m.v[c] - ym_m.v[c]));
    }

    const float nrm = phys_norm(F, H);

    // ---- MSE ----
    const f3 T = *(const f3*)(targ + (size_t)b * (ND * SXG)
                              + (size_t)(x * SXG + y * SYG + z * 3));
    const float dx = c_0.v[0] - T.v[0], dy = c_0.v[1] - T.v[1], dz = c_0.v[2] - T.v[2];
    const float ssq = dx * dx + dy * dy + dz * dz;

    const float invN = 1.0f / (float)NPTS;
    float val = 0.5f * ssq * (invN * (1.0f / 3.0f)) + 0.5f * nrm * invN;

    // ---- reduction: wave shuffle, then LDS across 8 waves ----
#pragma unroll
    for (int off = 32; off > 0; off >>= 1) val += __shfl_down(val, off, 64);

    __shared__ float wsum[8];
    if (lane == 0) wsum[wid] = val;
    __syncthreads();
    if (t == 0) {
        float acc = 0.0f;
#pragma unroll
        for (int w = 0; w < 8; w++) acc += wsum[w];
        atomicAdd(out, acc);
    }
}

extern "C" void kernel_launch(void* const* d_in, const int* in_sizes, int n_in,
                              void* d_out, int out_size, void* d_ws, size_t ws_size,
                              hipStream_t stream) {
    const float* pred = (const float*)d_in[0];
    const float* targ = (const float*)d_in[1];
    float* out = (float*)d_out;

    hipMemsetAsync(out, 0, sizeof(float), stream);

    const int blocks = (4 * 64 * 64) / 8;   // 2048 blocks, 8 columns each
    phys_loss_kernel<<<blocks, 512, 0, stream>>>(pred, targ, out);
}

// Round 7
// 32.356 us; speedup vs baseline: 1.3239x; 1.3239x over previous
//
#include <hip/hip_runtime.h>
#include <math.h>

#define ND 64
#define NPTS (4 * ND * ND * ND)   // 1,048,576
#define SXG (ND * ND * 3)         // 12288
#define SYG (ND * 3)              // 192

struct f3 { float v[3]; };

__device__ __forceinline__ f3 comb2(float a, const f3& X, float s, const f3& Y) {
    f3 r;
#pragma unroll
    for (int c = 0; c < 3; c++) r.v[c] = a * X.v[c] + s * Y.v[c];
    return r;
}
__device__ __forceinline__ f3 comb3(float a, const f3& X, float s, const f3& Y, float u, const f3& Z) {
    f3 r;
#pragma unroll
    for (int c = 0; c < 3; c++) r.v[c] = a * X.v[c] + s * Y.v[c] + u * Z.v[c];
    return r;
}

// physics residual norm; H symmetric [c][6]: 0=xx 1=yy 2=zz 3=xy 4=xz 5=yz
// (verified r3-r6, absmax 0.0)
__device__ __forceinline__ float phys_norm(const float F[3][3], const float H[3][6]) {
    constexpr int SYM[3][3] = {{0, 3, 4}, {3, 1, 5}, {4, 5, 2}};

    float cof[3][3];
#pragma unroll
    for (int i = 0; i < 3; i++) {
        const int i1 = (i + 1) % 3, i2 = (i + 2) % 3;
#pragma unroll
        for (int j = 0; j < 3; j++) {
            const int j1 = (j + 1) % 3, j2 = (j + 2) % 3;
            cof[i][j] = F[i1][j1] * F[i2][j2] - F[i1][j2] * F[i2][j1];
        }
    }

    float gc0[3][3], trg[3];
#pragma unroll
    for (int m = 0; m < 3; m++) {
        const int m1 = (m + 1) % 3, m2 = (m + 2) % 3;
        trg[m] = 0.0f;
#pragma unroll
        for (int i = 0; i < 3; i++) {
            const int i1 = (i + 1) % 3, i2 = (i + 2) % 3;
#pragma unroll
            for (int j = 0; j < 3; j++) {
                if (i == 0 || i == j) {
                    const float g = F[m2][i2] * H[m1][SYM[i1][j]] + F[m1][i1] * H[m2][SYM[i2][j]]
                                  - F[m2][i1] * H[m1][SYM[i2][j]] - F[m1][i2] * H[m2][SYM[i1][j]];
                    if (i == 0) gc0[m][j] = g;
                    if (i == j) trg[m] += g;
                }
            }
        }
    }

    const float J = F[0][0] * cof[0][0] + F[1][0] * cof[1][0] + F[2][0] * cof[2][0] + 1e-8f;
    const float invJ = 1.0f / J;

    float gJ[3];
#pragma unroll
    for (int j = 0; j < 3; j++) {
        gJ[j] = cof[0][0] * H[0][SYM[0][j]] + cof[1][0] * H[1][SYM[0][j]] + cof[2][0] * H[2][SYM[0][j]]
              + gc0[0][j] * F[0][0] + gc0[1][j] * F[1][0] + gc0[2][j] * F[2][0];
    }

    const float MU = 1000.0f, LMBD = 5000.0f;
    const float halfL = 0.5f * LMBD * (J * J - 1.0f);
    float r[3];
#pragma unroll
    for (int m = 0; m < 3; m++) {
        const float s1 = gJ[0] * cof[m][0] + gJ[1] * cof[m][1] + gJ[2] * cof[m][2];
        const float divInv = -invJ * invJ * s1 + invJ * trg[m];
        const float divF = H[m][0] + H[m][1] + H[m][2];
        float v = MU * (divF - divInv) + halfL * divInv + LMBD * s1;
        r[m] = (v != v) ? 0.0f : v;   // NaN -> 0
    }
    return sqrtf(r[0] * r[0] + r[1] * r[1] + r[2] * r[2]);
}

// one component: z-taps via wave shuffle (lane == z), in-register z-ghosts
// (verified r5, absmax 0.0)
__device__ __forceinline__ void comp_row(
        float vC, float vXP, float vXM, float vYP, float vYM,
        float vXP2, float vXM2, float vYP2, float vYM2,
        float vPP, float vPM, float vMP, float vMM,
        int ip1, int im1, int ip2, int im2,
        bool l0, bool l1, bool l62, bool l63,
        float G[3], float Hr[6]) {
    const float d1r = __shfl(vC, ip1, 64), u1r = __shfl(vC, im1, 64);
    const float d2r = __shfl(vC, ip2, 64), u2r = __shfl(vC, im2, 64);
    const float d1 = l63 ? 2.f * vC - u1r : d1r;
    const float u1 = l0  ? 2.f * vC - d1r : u1r;
    const float d2 = l63 ? 4.f * vC - 4.f * u1r + u2r : (l62 ? 2.f * d1 - vC : d2r);
    const float u2 = l0  ? 4.f * vC - 4.f * d1r + d2r : (l1 ? 2.f * u1 - vC : u2r);

    float ad = __shfl(vXP, ip1, 64), au = __shfl(vXP, im1, 64);
    const float XPd = l63 ? 2.f * vXP - au : ad;
    const float XPu = l0  ? 2.f * vXP - ad : au;
    ad = __shfl(vXM, ip1, 64); au = __shfl(vXM, im1, 64);
    const float XMd = l63 ? 2.f * vXM - au : ad;
    const float XMu = l0  ? 2.f * vXM - ad : au;
    ad = __shfl(vYP, ip1, 64); au = __shfl(vYP, im1, 64);
    const float YPd = l63 ? 2.f * vYP - au : ad;
    const float YPu = l0  ? 2.f * vYP - ad : au;
    ad = __shfl(vYM, ip1, 64); au = __shfl(vYM, im1, 64);
    const float YMd = l63 ? 2.f * vYM - au : ad;
    const float YMu = l0  ? 2.f * vYM - ad : au;

    G[0] = 0.5f * (vXP - vXM);
    G[1] = 0.5f * (vYP - vYM);
    G[2] = 0.5f * (d1 - u1);
    Hr[0] = 0.25f * (vXP2 + vXM2) - 0.5f * vC;
    Hr[1] = 0.25f * (vYP2 + vYM2) - 0.5f * vC;
    Hr[2] = 0.25f * (d2 + u2) - 0.5f * vC;
    Hr[3] = 0.25f * ((vPP - vMP) - (vPM - vMM));
    Hr[4] = 0.25f * ((XPd - XMd) - (XPu - XMu));
    Hr[5] = 0.25f * ((YPd - YMd) - (YPu - YMu));
}

__global__ __launch_bounds__(512) void phys_loss_kernel(
        const float* __restrict__ pred,
        const float* __restrict__ targ,
        float* __restrict__ out) {
    const int t = threadIdx.x;
    const int lane = t & 63;
    const int wid = t >> 6;
    const int w = blockIdx.x * 8 + wid;     // 2048 waves
    const int y = w & 63;
    const int xseg = (w >> 6) & 7;
    const int b = w >> 9;
    const int z = lane;
    const int X0 = xseg * 8;

    const float* __restrict__ pb = pred + (size_t)b * (ND * SXG);
    const int yc1p = min(y + 1, 63), yc1m = max(y - 1, 0);
    const int yc2p = min(y + 2, 63), yc2m = max(y - 2, 0);

#define LDP(gx, gy) (*(const f3*)(pb + (size_t)((gx) * SXG + (gy) * SYG + z * 3)))

    // y-ghost fix for a (yp,ym) pair at some x-level with center col cg there
    auto fixy1 = [&](const f3& ypl, const f3& yml, const f3& cg, f3& ypc, f3& ymc) {
        if (y == 0)       { ypc = ypl; ymc = comb2(2.f, cg, -1.f, ypl); }
        else if (y == 63) { ymc = yml; ypc = comb2(2.f, cg, -1.f, yml); }
        else              { ypc = ypl; ymc = yml; }
    };
    // y-ghost fix for (yp2,ym2) at current x-level (c0/yp1/ym1 at same level)
    auto fixy2 = [&](const f3& yp2l, const f3& ym2l, const f3& c0,
                     const f3& yp1, const f3& ym1, f3& o_p, f3& o_m) {
        if (y == 0)       { o_p = yp2l; o_m = comb3(4.f, c0, -4.f, yp1, 1.f, yp2l); }
        else if (y == 1)  { o_p = yp2l; o_m = comb2(2.f, ym1, -1.f, c0); }
        else if (y == 62) { o_m = ym2l; o_p = comb2(2.f, yp1, -1.f, c0); }
        else if (y == 63) { o_m = ym2l; o_p = comb3(4.f, c0, -4.f, ym1, 1.f, ym2l); }
        else              { o_p = yp2l; o_m = ym2l; }
    };

    // ---- prologue: windows for x0 = X0 ----
    f3 cc[5], cyp[3], cym[3], yp2, ym2;
    if (X0 == 0) {
        cc[2] = LDP(0, y); cc[3] = LDP(1, y); cc[4] = LDP(2, y);
        cc[1] = comb2(2.f, cc[2], -1.f, cc[3]);
        cc[0] = comb3(4.f, cc[2], -4.f, cc[3], 1.f, cc[4]);
        { f3 a = LDP(0, yc1p), bq = LDP(0, yc1m); fixy1(a, bq, cc[2], cyp[1], cym[1]); }
        { f3 a = LDP(1, yc1p), bq = LDP(1, yc1m); fixy1(a, bq, cc[3], cyp[2], cym[2]); }
        cyp[0] = comb2(2.f, cyp[1], -1.f, cyp[2]);
        cym[0] = comb2(2.f, cym[1], -1.f, cym[2]);
    } else {
#pragma unroll
        for (int k = 0; k < 5; k++) cc[k] = LDP(X0 - 2 + k, y);
#pragma unroll
        for (int k = 0; k < 3; k++) {
            f3 a = LDP(X0 - 1 + k, yc1p), bq = LDP(X0 - 1 + k, yc1m);
            fixy1(a, bq, cc[k + 1], cyp[k], cym[k]);
        }
    }
    { f3 a = LDP(X0, yc2p), bq = LDP(X0, yc2m);
      fixy2(a, bq, cc[2], cyp[1], cym[1], yp2, ym2); }

    const bool l0 = (z == 0), l1 = (z == 1), l62 = (z == 62), l63 = (z == 63);
    const int ip1 = (lane + 1) & 63, im1 = (lane + 63) & 63;
    const int ip2 = (lane + 2) & 63, im2 = (lane + 62) & 63;

    float accn = 0.f, accs = 0.f;

#pragma unroll 2
    for (int i = 0; i < 8; i++) {
        const int x0 = X0 + i;

        // ---- prefetch raw (clamped) columns for next step ----
        f3 cin, ypin, ymin, yp2in, ym2in;
        if (i < 7) {
            const int gxc = min(x0 + 3, 63);
            const int gx1 = min(x0 + 2, 63);
            cin  = LDP(gxc, y);
            ypin = LDP(gx1, yc1p);  ymin = LDP(gx1, yc1m);
            yp2in = LDP(x0 + 1, yc2p);  ym2in = LDP(x0 + 1, yc2m);
        }
        const f3 T = *(const f3*)(targ + (size_t)b * (ND * SXG)
                                  + (size_t)(x0 * SXG + y * SYG + z * 3));

        // ---- compute current step from windows ----
        float F[3][3], H[3][6], G[3];
        comp_row(cc[2].v[0], cc[3].v[0], cc[1].v[0], cyp[1].v[0], cym[1].v[0],
                 cc[4].v[0], cc[0].v[0], yp2.v[0], ym2.v[0],
                 cyp[2].v[0], cym[2].v[0], cyp[0].v[0], cym[0].v[0],
                 ip1, im1, ip2, im2, l0, l1, l62, l63, G, H[0]);
        F[0][0] = G[0] + 1.f; F[0][1] = G[1]; F[0][2] = G[2];
        comp_row(cc[2].v[1], cc[3].v[1], cc[1].v[1], cyp[1].v[1], cym[1].v[1],
                 cc[4].v[1], cc[0].v[1], yp2.v[1], ym2.v[1],
                 cyp[2].v[1], cym[2].v[1], cyp[0].v[1], cym[0].v[1],
                 ip1, im1, ip2, im2, l0, l1, l62, l63, G, H[1]);
        F[1][0] = G[0]; F[1][1] = G[1] + 1.f; F[1][2] = G[2];
        comp_row(cc[2].v[2], cc[3].v[2], cc[1].v[2], cyp[1].v[2], cym[1].v[2],
                 cc[4].v[2], cc[0].v[2], yp2.v[2], ym2.v[2],
                 cyp[2].v[2], cym[2].v[2], cyp[0].v[2], cym[0].v[2],
                 ip1, im1, ip2, im2, l0, l1, l62, l63, G, H[2]);
        F[2][0] = G[0]; F[2][1] = G[1]; F[2][2] = G[2] + 1.f;

        accn += phys_norm(F, H);

        const float dx = cc[2].v[0] - T.v[0];
        const float dy = cc[2].v[1] - T.v[1];
        const float dz = cc[2].v[2] - T.v[2];
        accs += dx * dx + dy * dy + dz * dz;

        // ---- commit prefetched data into windows for next step ----
        if (i < 7) {
            cc[0] = cc[1]; cc[1] = cc[2]; cc[2] = cc[3]; cc[3] = cc[4];
            cyp[0] = cyp[1]; cyp[1] = cyp[2];
            cym[0] = cym[1]; cym[1] = cym[2];
            const int nx0 = x0 + 1;
            // new center at nx0+2 (x-ghost past 63)
            if (nx0 + 2 <= 63)      cc[4] = cin;
            else if (nx0 + 2 == 64) cc[4] = comb2(2.f, cc[3], -1.f, cc[2]);
            else                    cc[4] = comb3(4.f, cc[2], -4.f, cc[1], 1.f, cc[0]);
            // new yp/ym at nx0+1
            if (nx0 + 1 <= 63) {
                fixy1(ypin, ymin, cc[3], cyp[2], cym[2]);
            } else {
                cyp[2] = comb2(2.f, cyp[1], -1.f, cyp[0]);
                cym[2] = comb2(2.f, cym[1], -1.f, cym[0]);
            }
            // new yp2/ym2 at nx0
            fixy2(yp2in, ym2in, cc[2], cyp[1], cym[1], yp2, ym2);
        }
    }
#undef LDP

    const float invN = 1.0f / (float)NPTS;
    float val = 0.5f * accs * (invN * (1.0f / 3.0f)) + 0.5f * accn * invN;

    // ---- reduction: wave shuffle, then LDS across 8 waves ----
#pragma unroll
    for (int off = 32; off > 0; off >>= 1) val += __shfl_down(val, off, 64);

    __shared__ float wsum[8];
    if (lane == 0) wsum[wid] = val;
    __syncthreads();
    if (t == 0) {
        float acc = 0.0f;
#pragma unroll
        for (int wq = 0; wq < 8; wq++) acc += wsum[wq];
        atomicAdd(out, acc);
    }
}

extern "C" void kernel_launch(void* const* d_in, const int* in_sizes, int n_in,
                              void* d_out, int out_size, void* d_ws, size_t ws_size,
                              hipStream_t stream) {
    const float* pred = (const float*)d_in[0];
    const float* targ = (const float*)d_in[1];
    float* out = (float*)d_out;

    hipMemsetAsync(out, 0, sizeof(float), stream);

    const int blocks = 256;   // 2048 waves, one (b,y,xseg) strip each
    phys_loss_kernel<<<blocks, 512, 0, stream>>>(pred, targ, out);
}